// Round 4
// baseline (222.027 us; speedup 1.0000x reference)
//
#include <hip/hip_runtime.h>
#include <math.h>

// Problem constants (from reference): w is [B, N] float32, L = 1.0
#define B_ROWS 16384
#define N_COLS 2048

// ---- ws layout (floats) ----
// Partials: 1024 rowchunks x 4096 floats ([0,2048)=colsum, [2048,4096)=colsum2)
#define WS_PART     0
#define WS_GRP      (1024 * 4096)                // 16 groups x 4096
#define WS_MEAN     (WS_GRP + 16 * 4096)         // 2048
#define WS_INVSTD   (WS_MEAN + N_COLS)           // 2048
#define WS_RP       (WS_INVSTD + N_COLS)         // 2048 rowpass block partials
// total ~17 MB

// ---------------- Pass 1: per-rowchunk column partial sums ----------------
// 2048 blocks = 1024 rowchunks x 2 colgroups, 16 rows each. Two 8-deep
// load/consume-split batches; float4 accumulators keep VGPR ~<64 so we get
// 8 waves/SIMD (full occupancy) AND 8 outstanding dwordx4 per wave.
constexpr int K1_ROWCHUNKS = 1024;
constexpr int K1_ROWS = B_ROWS / K1_ROWCHUNKS;  // = 16

__global__ __launch_bounds__(256) void colstats_kernel(
    const float* __restrict__ w, float* __restrict__ part) {
  const int cg = blockIdx.x & 1;
  const int rc = blockIdx.x >> 1;
  const int col4 = cg * 256 + threadIdx.x;  // float4 column index in [0,512)
  const float4* __restrict__ w4 = reinterpret_cast<const float4*>(w) + col4;
  const size_t stride = N_COLS / 4;
  const size_t base = (size_t)rc * K1_ROWS * stride;

  float sx = 0.f, sy = 0.f, sz = 0.f, sw = 0.f;
  float qx = 0.f, qy = 0.f, qz = 0.f, qw = 0.f;
#pragma unroll
  for (int batch = 0; batch < K1_ROWS / 8; ++batch) {
    float4 v[8];
#pragma unroll
    for (int i = 0; i < 8; ++i)
      v[i] = w4[base + (size_t)(batch * 8 + i) * stride];
#pragma unroll
    for (int i = 0; i < 8; ++i) {
      sx += v[i].x; sy += v[i].y; sz += v[i].z; sw += v[i].w;
      qx = fmaf(v[i].x, v[i].x, qx);
      qy = fmaf(v[i].y, v[i].y, qy);
      qz = fmaf(v[i].z, v[i].z, qz);
      qw = fmaf(v[i].w, v[i].w, qw);
    }
  }
  float4* __restrict__ p4 = reinterpret_cast<float4*>(part);
  p4[(size_t)rc * 1024 + col4] = make_float4(sx, sy, sz, sw);
  p4[(size_t)rc * 1024 + 512 + col4] = make_float4(qx, qy, qz, qw);
}

// ---------------- Reduce stage 1: 1024 rowchunks -> 16 groups ----------------
__global__ __launch_bounds__(256) void reduce1_kernel(
    const float* __restrict__ part, float* __restrict__ grp) {
  const int t = blockIdx.x * 256 + threadIdx.x;  // 0..16383
  const int g = t >> 10;                          // group 0..15 (64 rc each)
  const int pos = t & 1023;                       // float4 position in [0,1024)
  const float4* __restrict__ p4 = reinterpret_cast<const float4*>(part);
  float ax = 0.f, ay = 0.f, az = 0.f, aw = 0.f;
  for (int b = 0; b < 8; ++b) {
    float4 v[8];
#pragma unroll
    for (int i = 0; i < 8; ++i)
      v[i] = p4[(size_t)(g * 64 + b * 8 + i) * 1024 + pos];
#pragma unroll
    for (int i = 0; i < 8; ++i) {
      ax += v[i].x; ay += v[i].y; az += v[i].z; aw += v[i].w;
    }
  }
  reinterpret_cast<float4*>(grp)[(size_t)g * 1024 + pos] =
      make_float4(ax, ay, az, aw);
}

// ---------------- Finalize: 16 groups -> mean / invstd ----------------
__global__ __launch_bounds__(256) void finalize_kernel(
    const float* __restrict__ grp, float* __restrict__ ws) {
  const int n = blockIdx.x * 256 + threadIdx.x;  // column in [0,2048)
  float s = 0.f, q = 0.f;
#pragma unroll
  for (int g = 0; g < 16; ++g) {
    s += grp[g * 4096 + n];
    q += grp[g * 4096 + 2048 + n];
  }
  const float inv_b = 1.0f / (float)B_ROWS;
  float mean = s * inv_b;
  float var = q * inv_b - mean * mean;
  ws[WS_MEAN + n] = mean;
  ws[WS_INVSTD + n] = 1.0f / sqrtf(var);
}

// ---------------- Pass 2: per-row s, s2 -> |pair_mean|, block partials ----------------
constexpr int K3_BLOCKS = 2048;
constexpr int ROWS_PER_BLOCK = B_ROWS / K3_BLOCKS;  // = 8 (2 rows per wave)

__global__ __launch_bounds__(256) void rowpass_kernel(
    const float* __restrict__ w, const float* __restrict__ ws,
    float* __restrict__ partials) {
  __shared__ float4 sm_mean[N_COLS / 4];  // 8 KiB
  __shared__ float4 sm_inv[N_COLS / 4];   // 8 KiB
  __shared__ float warpsum[4];

  const float4* __restrict__ g_mean = reinterpret_cast<const float4*>(ws + WS_MEAN);
  const float4* __restrict__ g_inv = reinterpret_cast<const float4*>(ws + WS_INVSTD);
  for (int i = threadIdx.x; i < N_COLS / 4; i += 256) {
    sm_mean[i] = g_mean[i];
    sm_inv[i] = g_inv[i];
  }
  __syncthreads();

  const int wid = threadIdx.x >> 6;
  const int lane = threadIdx.x & 63;
  constexpr float inv_pairs = 1.0f / ((float)N_COLS * (float)(N_COLS - 1));

  const int row_a = blockIdx.x * ROWS_PER_BLOCK + wid * 2;
  const float4* __restrict__ ra =
      reinterpret_cast<const float4*>(w + (size_t)row_a * N_COLS);
  const float4* __restrict__ rb =
      reinterpret_cast<const float4*>(w + (size_t)(row_a + 1) * N_COLS);

  // Batch all 16 loads (2 rows x 8) before any consumer.
  float4 va[8], vb[8];
#pragma unroll
  for (int k = 0; k < 8; ++k) va[k] = ra[lane + k * 64];
#pragma unroll
  for (int k = 0; k < 8; ++k) vb[k] = rb[lane + k * 64];

  float sa = 0.f, qa = 0.f, sb = 0.f, qb = 0.f;
#pragma unroll
  for (int k = 0; k < 8; ++k) {
    const int idx = lane + k * 64;
    float4 m = sm_mean[idx];
    float4 iv = sm_inv[idx];
    float ax = (va[k].x - m.x) * iv.x, ay = (va[k].y - m.y) * iv.y;
    float az = (va[k].z - m.z) * iv.z, aw = (va[k].w - m.w) * iv.w;
    float bx = (vb[k].x - m.x) * iv.x, by = (vb[k].y - m.y) * iv.y;
    float bz = (vb[k].z - m.z) * iv.z, bw = (vb[k].w - m.w) * iv.w;
    sa += (ax + ay) + (az + aw);
    qa += fmaf(ax, ax, fmaf(ay, ay, fmaf(az, az, aw * aw)));
    sb += (bx + by) + (bz + bw);
    qb += fmaf(bx, bx, fmaf(by, by, fmaf(bz, bz, bw * bw)));
  }
#pragma unroll
  for (int off = 32; off > 0; off >>= 1) {
    sa += __shfl_xor(sa, off);
    qa += __shfl_xor(qa, off);
    sb += __shfl_xor(sb, off);
    qb += __shfl_xor(qb, off);
  }
  float pm_a = (sa * sa - qa) * inv_pairs;
  float pm_b = (sb * sb - qb) * inv_pairs;
  float acc = fabsf(pm_a) + fabsf(pm_b);

  if (lane == 0) warpsum[wid] = acc;
  __syncthreads();
  if (threadIdx.x == 0)
    partials[blockIdx.x] = (warpsum[0] + warpsum[1]) + (warpsum[2] + warpsum[3]);
}

// ---------------- Final reduce ----------------
__global__ __launch_bounds__(256) void final_reduce_kernel(
    const float* __restrict__ partials, float* __restrict__ out) {
  __shared__ float warpsum[4];
  float acc = 0.f;
  for (int i = threadIdx.x; i < K3_BLOCKS; i += 256) acc += partials[i];
#pragma unroll
  for (int off = 32; off > 0; off >>= 1) acc += __shfl_xor(acc, off);
  const int wid = threadIdx.x >> 6;
  const int lane = threadIdx.x & 63;
  if (lane == 0) warpsum[wid] = acc;
  __syncthreads();
  if (threadIdx.x == 0) {
    float total = (warpsum[0] + warpsum[1]) + (warpsum[2] + warpsum[3]);
    out[0] = total * (1.0f / (float)B_ROWS);  // L = 1.0
  }
}

extern "C" void kernel_launch(void* const* d_in, const int* in_sizes, int n_in,
                              void* d_out, int out_size, void* d_ws, size_t ws_size,
                              hipStream_t stream) {
  const float* w = reinterpret_cast<const float*>(d_in[0]);
  float* out = reinterpret_cast<float*>(d_out);
  float* ws = reinterpret_cast<float*>(d_ws);

  colstats_kernel<<<K1_ROWCHUNKS * 2, 256, 0, stream>>>(w, ws + WS_PART);
  reduce1_kernel<<<64, 256, 0, stream>>>(ws + WS_PART, ws + WS_GRP);
  finalize_kernel<<<8, 256, 0, stream>>>(ws + WS_GRP, ws);
  rowpass_kernel<<<K3_BLOCKS, 256, 0, stream>>>(w, ws, ws + WS_RP);
  final_reduce_kernel<<<1, 256, 0, stream>>>(ws + WS_RP, out);
}